// Round 1
// baseline (17347.693 us; speedup 1.0000x reference)
//
#include <hip/hip_runtime.h>
#include <stdint.h>

// LSTM forward, B=128 T=512 F=256 H=512, Keras gate order i,f,g,o.
// Plan:
//  kernel lstm_xz : xz[B*T,2048] = x @ kernel + bias  (split-bf16 MFMA, fp16 output in ws)
//  kernel lstm_rec: persistent scan. 8 independent batch-row groups (16 rows each),
//                   64 blocks per group (8 h-cols each), per-group global barrier per step.
//                   R-slice resident in LDS (bf16), c in registers, h ping-pong (bf16) in ws.
// ws layout: [0, 256MB) xz fp16 | hbuf 2x128x512 bf16 (256KB) | barrier 2KB  => ~256.3 MB

#define Bb 128
#define Tt 512
#define Ff 256
#define Hh 512
#define G4 2048

typedef __attribute__((ext_vector_type(8))) short short8;
typedef __attribute__((ext_vector_type(4))) float floatx4;

__device__ __forceinline__ unsigned short f2bf(float f) {
    unsigned u = __float_as_uint(f);
    return (unsigned short)((u + 0x7FFFu + ((u >> 16) & 1u)) >> 16);
}
__device__ __forceinline__ float bf2f(unsigned short h) {
    return __uint_as_float(((unsigned)h) << 16);
}
__device__ __forceinline__ float sigm(float x) { return 1.f / (1.f + __expf(-x)); }
__device__ __forceinline__ float tanh_f(float x) {
    float e = __expf(-2.f * fabsf(x));
    return copysignf((1.f - e) / (1.f + e), x);
}

// ---------------------------------------------------------------------------
// Kernel A: xz = x @ w + bias, stored fp16. Split-bf16 (x=hi+lo) for accuracy.
// 128x128 tile / block, BK=32 (orig k), K=256. Grid 512x16 = 8192 blocks.
// ---------------------------------------------------------------------------
__global__ __launch_bounds__(256, 2) void lstm_xz(
    const float* __restrict__ x, const float* __restrict__ w,
    const float* __restrict__ bias, _Float16* __restrict__ xzh)
{
    __shared__ unsigned short Ahi[128 * 40];   // pitch 40: 16B-aligned rows, 2-way-free banks
    __shared__ unsigned short Alo[128 * 40];
    __shared__ unsigned short Wt [128 * 40];   // Wt[n][k] (transposed for B-frags)

    const int tid = threadIdx.x;
    // XCD-aware swizzle: each XCD works a 64-m-tile slice, n-outer/m-inner in
    // super-blocks of 8 m-tiles so the x slice (~1MB) stays L2-resident.
    int idx = blockIdx.x;
    int xcd = idx & 7;
    int chunk = idx >> 3;          // 0..1023
    int msup = chunk >> 7;         // 0..7
    int s = chunk & 127;
    int nt = s >> 3;               // 0..15
    int mi0 = s & 7;
    int mt = xcd * 64 + msup * 8 + mi0;   // 0..511
    const int m0 = mt << 7;
    const int n0 = nt << 7;

    const int lane = tid & 63;
    const int wv = tid >> 6;           // 4 waves, 2x2 wave grid (64x64 each)
    const int wm = wv >> 1, wn = wv & 1;
    const int cB = lane & 15, kgrp = lane >> 4;

    floatx4 acc[4][4];
#pragma unroll
    for (int i = 0; i < 4; ++i)
#pragma unroll
        for (int j = 0; j < 4; ++j) acc[i][j] = (floatx4){0.f, 0.f, 0.f, 0.f};

    float bv[4];
#pragma unroll
    for (int ni = 0; ni < 4; ++ni) bv[ni] = bias[n0 + wn * 64 + ni * 16 + cB];

    for (int it = 0; it < 8; ++it) {
        const int k0 = it * 32;
        // stage x tile (128 rows x 32 k, fp32) -> hi/lo bf16 planes
#pragma unroll
        for (int sw = 0; sw < 4; ++sw) {
            int e = sw * 256 + tid;          // 0..1023
            int row = e >> 3, kq = e & 7;
            float4 v = *((const float4*)(x + (size_t)(m0 + row) * Ff + k0) + kq);
            unsigned short h0 = f2bf(v.x), h1 = f2bf(v.y), h2 = f2bf(v.z), h3 = f2bf(v.w);
            unsigned short l0 = f2bf(v.x - bf2f(h0)), l1 = f2bf(v.y - bf2f(h1));
            unsigned short l2 = f2bf(v.z - bf2f(h2)), l3 = f2bf(v.w - bf2f(h3));
            uint2 ph, pl;
            ph.x = (unsigned)h0 | ((unsigned)h1 << 16); ph.y = (unsigned)h2 | ((unsigned)h3 << 16);
            pl.x = (unsigned)l0 | ((unsigned)l1 << 16); pl.y = (unsigned)l2 | ((unsigned)l3 << 16);
            *(uint2*)(&Ahi[row * 40 + kq * 4]) = ph;
            *(uint2*)(&Alo[row * 40 + kq * 4]) = pl;
        }
        // stage w tile (32 k x 128 n), transposed into Wt[n][k]
#pragma unroll
        for (int sw = 0; sw < 4; ++sw) {
            int e = sw * 256 + tid;
            int kr = e >> 5, nq = e & 31;
            float4 v = *((const float4*)(w + (size_t)(k0 + kr) * G4 + n0) + nq);
            int nb = nq * 4;
            Wt[(nb + 0) * 40 + kr] = f2bf(v.x);
            Wt[(nb + 1) * 40 + kr] = f2bf(v.y);
            Wt[(nb + 2) * 40 + kr] = f2bf(v.z);
            Wt[(nb + 3) * 40 + kr] = f2bf(v.w);
        }
        __syncthreads();

        short8 bfr[4];
#pragma unroll
        for (int ni = 0; ni < 4; ++ni)
            bfr[ni] = *(const short8*)(&Wt[(wn * 64 + ni * 16 + cB) * 40 + kgrp * 8]);
#pragma unroll
        for (int mi = 0; mi < 4; ++mi) {
            short8 ah = *(const short8*)(&Ahi[(wm * 64 + mi * 16 + cB) * 40 + kgrp * 8]);
            short8 al = *(const short8*)(&Alo[(wm * 64 + mi * 16 + cB) * 40 + kgrp * 8]);
#pragma unroll
            for (int ni = 0; ni < 4; ++ni) {
                acc[mi][ni] = __builtin_amdgcn_mfma_f32_16x16x32_bf16(ah, bfr[ni], acc[mi][ni], 0, 0, 0);
                acc[mi][ni] = __builtin_amdgcn_mfma_f32_16x16x32_bf16(al, bfr[ni], acc[mi][ni], 0, 0, 0);
            }
        }
        __syncthreads();
    }
    // epilogue: +bias, store fp16. C layout: col=lane&15, row=(lane>>4)*4+reg
#pragma unroll
    for (int mi = 0; mi < 4; ++mi)
#pragma unroll
        for (int ni = 0; ni < 4; ++ni) {
            int rowb = m0 + wm * 64 + mi * 16 + kgrp * 4;
            int col = n0 + wn * 64 + ni * 16 + cB;
#pragma unroll
            for (int rr = 0; rr < 4; ++rr)
                xzh[(size_t)(rowb + rr) * G4 + col] = (_Float16)(acc[mi][ni][rr] + bv[ni]);
        }
}

// ---------------------------------------------------------------------------
// Kernel R: persistent scan. Grid 512 = 8 row-groups x 64 col-blocks.
// Block: 256 thr (4 waves: tile t2 in {0,1} x k-half kh in {0,1}).
// Block owns 16 batch rows x 8 h-cols; z-tile packing: tile0 cols = (i 0..7 | f 0..7),
// tile1 cols = (g 0..7 | o 0..7). LDS: Rlds 32x520 bf16 + hlds 16x520 bf16 + zbuf 4x256 f32.
// ---------------------------------------------------------------------------
__global__ __launch_bounds__(256, 2) void lstm_rec(
    const _Float16* __restrict__ xzh, const float* __restrict__ rk,
    unsigned short* __restrict__ hbuf, unsigned* __restrict__ bar,
    float* __restrict__ out)
{
    __shared__ unsigned short Rlds[32 * 520];
    __shared__ unsigned short hlds[16 * 520];
    __shared__ float zbuf[4 * 256];

    const int tid = threadIdx.x;
    const int idx = blockIdx.x;
    const int rg = idx & 7;          // row group (maps to XCD under round-robin; perf only)
    const int cb = idx >> 3;         // 0..63
    const int b0 = rg * 16;
    const int hc0 = cb * 8;

    const int lane = tid & 63;
    const int wv = tid >> 6;         // 0..3
    const int t2 = wv & 1;           // which packed z-tile
    const int kh = wv >> 1;          // k half: [0,256) or [256,512)
    const int cB = lane & 15, kgrp = lane >> 4;

    // preload R slice: Rlds[n][k], n = t2*16+sub, gate = t2*2 + (sub>>3), hcol = sub&7
    for (int e = tid; e < 32 * 512; e += 256) {
        int k = e >> 5, n = e & 31;
        int gate = ((n >> 4) << 1) | ((n >> 3) & 1);
        int col = gate * 512 + hc0 + (n & 7);
        Rlds[n * 520 + k] = f2bf(rk[(size_t)k * G4 + col]);
    }

    unsigned short* hb0 = hbuf;
    unsigned short* hb1 = hbuf + (size_t)Bb * Hh;
    unsigned* cnt = bar + rg * 32;
    unsigned* gen = bar + 256 + rg * 32;
    unsigned local_gen = 0;

    const int r = tid >> 3, cc = tid & 7;   // elementwise ownership (tid < 128)
    const int b = b0 + r;
    const bool ew = (tid < 128);
    float creg = 0.f;
    float xzr[4];
    if (ew) {
#pragma unroll
        for (int g = 0; g < 4; ++g)
            xzr[g] = (float)xzh[((size_t)b * Tt + 0) * G4 + g * 512 + hc0 + cc];
    }
    __syncthreads();

    for (int t = 0; t < Tt; ++t) {
        // stage h tile (16 rows x 512, bf16) -> hlds
        const unsigned short* hrd = (t & 1) ? hb1 : hb0;
        unsigned short* hwr = (t & 1) ? hb0 : hb1;
        const uint4* src = (const uint4*)(hrd + (size_t)b0 * Hh);
#pragma unroll
        for (int sw = 0; sw < 4; ++sw) {
            int e = sw * 256 + tid;          // 1024 chunks of 8 bf16
            int row = e >> 6, c8 = e & 63;
            uint4 v = src[e];
            *(uint4*)(&hlds[row * 520 + c8 * 8]) = v;
        }
        __syncthreads();

        // z-tile GEMM: 1 MFMA-tile per wave, K-half of 256
        floatx4 acc = (floatx4){0.f, 0.f, 0.f, 0.f};
        {
            const unsigned short* ap = &hlds[cB * 520 + kh * 256 + kgrp * 8];
            const unsigned short* bp = &Rlds[(t2 * 16 + cB) * 520 + kh * 256 + kgrp * 8];
#pragma unroll
            for (int kk = 0; kk < 8; ++kk) {
                short8 a = *(const short8*)(ap + kk * 32);
                short8 bb = *(const short8*)(bp + kk * 32);
                acc = __builtin_amdgcn_mfma_f32_16x16x32_bf16(a, bb, acc, 0, 0, 0);
            }
        }
        {
            float* zp = &zbuf[wv * 256 + kgrp * 64 + cB];  // row=kgrp*4+reg, col=cB
            zp[0]  = acc[0];
            zp[16] = acc[1];
            zp[32] = acc[2];
            zp[48] = acc[3];
        }
        __syncthreads();

        if (ew) {
            int base = r * 16 + cc;
            float zi = zbuf[base]           + zbuf[512 + base]       + xzr[0];
            float zf = zbuf[base + 8]       + zbuf[512 + base + 8]   + xzr[1];
            float zg = zbuf[256 + base]     + zbuf[768 + base]       + xzr[2];
            float zo = zbuf[256 + base + 8] + zbuf[768 + base + 8]   + xzr[3];
            float i_ = sigm(zi), f_ = sigm(zf), g_ = tanh_f(zg), o_ = sigm(zo);
            creg = f_ * creg + i_ * g_;
            float hv = o_ * tanh_f(creg);
            out[((size_t)b * Tt + t) * Hh + hc0 + cc] = hv;
            hwr[(size_t)b * Hh + hc0 + cc] = f2bf(hv);
            if (t < Tt - 1) {
                // prefetch next step's xz: HBM latency hides behind barrier+GEMM
#pragma unroll
                for (int g = 0; g < 4; ++g)
                    xzr[g] = (float)xzh[((size_t)b * Tt + (t + 1)) * G4 + g * 512 + hc0 + cc];
            } else {
                float* hl = out + (size_t)Bb * Tt * Hh;
                float* cl = hl + (size_t)Bb * Hh;
                hl[(size_t)b * Hh + hc0 + cc] = hv;
                cl[(size_t)b * Hh + hc0 + cc] = creg;
            }
        }
        if (t == Tt - 1) break;

        // per-row-group barrier (64 blocks), device-scope for XCD-mapping safety
        __syncthreads();                 // all waves' h stores issued (vmcnt drained)
        if (tid == 0) {
            __threadfence();             // agent-scope release of this block's h writes
            unsigned target = ++local_gen;
            unsigned old = __hip_atomic_fetch_add(cnt, 1u, __ATOMIC_ACQ_REL, __HIP_MEMORY_SCOPE_AGENT);
            if (old == 63u) {
                __hip_atomic_store(cnt, 0u, __ATOMIC_RELAXED, __HIP_MEMORY_SCOPE_AGENT);
                __hip_atomic_store(gen, target, __ATOMIC_RELEASE, __HIP_MEMORY_SCOPE_AGENT);
            } else {
                while (__hip_atomic_load(gen, __ATOMIC_ACQUIRE, __HIP_MEMORY_SCOPE_AGENT) < target)
                    __builtin_amdgcn_s_sleep(2);
            }
        }
        __syncthreads();
    }
}

// ---------------------------------------------------------------------------
extern "C" void kernel_launch(void* const* d_in, const int* in_sizes, int n_in,
                              void* d_out, int out_size, void* d_ws, size_t ws_size,
                              hipStream_t stream) {
    (void)in_sizes; (void)n_in; (void)out_size; (void)ws_size;
    const float* x    = (const float*)d_in[0];
    const float* w    = (const float*)d_in[1];
    const float* rk   = (const float*)d_in[2];
    const float* bias = (const float*)d_in[3];
    float* out = (float*)d_out;

    char* ws = (char*)d_ws;
    const size_t XZ_BYTES   = (size_t)Bb * Tt * G4 * sizeof(_Float16);   // 268,435,456
    const size_t HBUF_BYTES = (size_t)2 * Bb * Hh * sizeof(unsigned short); // 262,144
    const size_t BAR_BYTES  = 2048;

    _Float16* xzh = (_Float16*)ws;
    unsigned short* hbuf = (unsigned short*)(ws + XZ_BYTES);
    unsigned* bar = (unsigned*)(ws + XZ_BYTES + HBUF_BYTES);

    // zero h0 ping-pong + barrier state (ws is poisoned 0xAA before every call)
    hipMemsetAsync(ws + XZ_BYTES, 0, HBUF_BYTES + BAR_BYTES, stream);

    lstm_xz<<<dim3(8192), dim3(256), 0, stream>>>(x, w, bias, xzh);
    lstm_rec<<<dim3(512), dim3(256), 0, stream>>>(xzh, rk, hbuf, bar, out);
}

// Round 2
// 3934.933 us; speedup vs baseline: 4.4086x; 4.4086x over previous
//
#include <hip/hip_runtime.h>
#include <stdint.h>

// LSTM forward, B=128 T=512 F=256 H=512, Keras gate order i,f,g,o.
//  kernel lstm_xz : xz[B*T,2048] = x @ kernel + bias  (split-bf16 MFMA, fp16 output in ws)
//  kernel lstm_rec: persistent scan. 8 row groups (16 rows) x 64 col-blocks (8 h-cols).
//    R0: FENCE-FREE cross-block sync. All cross-block data (h ping-pong, barrier words)
//    uses device-scope RELAXED atomics (sc1, bypasses non-coherent per-XCD L2). No
//    __threadfence / acquire / release -> no buffer_wbl2 / buffer_inv L2 walks (these
//    were ~32us/step in round 1). Ordering via s_waitcnt vmcnt(0): sc1 store completion
//    == arrival at device coherence point. Barrier counter is monotonic (no reset).
// ws layout: [0, 256MB) xz fp16 | hbuf 2x128x512 bf16 (256KB) | barrier 2KB

#define Bb 128
#define Tt 512
#define Ff 256
#define Hh 512
#define G4 2048

typedef __attribute__((ext_vector_type(8))) short short8;
typedef __attribute__((ext_vector_type(4))) float floatx4;

__device__ __forceinline__ unsigned short f2bf(float f) {
    unsigned u = __float_as_uint(f);
    return (unsigned short)((u + 0x7FFFu + ((u >> 16) & 1u)) >> 16);
}
__device__ __forceinline__ float bf2f(unsigned short h) {
    return __uint_as_float(((unsigned)h) << 16);
}
__device__ __forceinline__ float sigm(float x) { return 1.f / (1.f + __expf(-x)); }
__device__ __forceinline__ float tanh_f(float x) {
    float e = __expf(-2.f * fabsf(x));
    return copysignf((1.f - e) / (1.f + e), x);
}

// ---------------------------------------------------------------------------
// Kernel A: xz = x @ w + bias, stored fp16. Split-bf16 (x=hi+lo) for accuracy.
// 128x128 tile / block, BK=32 (orig k), K=256. Grid 8192 blocks.
// ---------------------------------------------------------------------------
__global__ __launch_bounds__(256, 2) void lstm_xz(
    const float* __restrict__ x, const float* __restrict__ w,
    const float* __restrict__ bias, _Float16* __restrict__ xzh)
{
    __shared__ unsigned short Ahi[128 * 40];
    __shared__ unsigned short Alo[128 * 40];
    __shared__ unsigned short Wt [128 * 40];

    const int tid = threadIdx.x;
    int idx = blockIdx.x;
    int xcd = idx & 7;
    int chunk = idx >> 3;
    int msup = chunk >> 7;
    int s = chunk & 127;
    int nt = s >> 3;
    int mi0 = s & 7;
    int mt = xcd * 64 + msup * 8 + mi0;
    const int m0 = mt << 7;
    const int n0 = nt << 7;

    const int lane = tid & 63;
    const int wv = tid >> 6;
    const int wm = wv >> 1, wn = wv & 1;
    const int cB = lane & 15, kgrp = lane >> 4;

    floatx4 acc[4][4];
#pragma unroll
    for (int i = 0; i < 4; ++i)
#pragma unroll
        for (int j = 0; j < 4; ++j) acc[i][j] = (floatx4){0.f, 0.f, 0.f, 0.f};

    float bv[4];
#pragma unroll
    for (int ni = 0; ni < 4; ++ni) bv[ni] = bias[n0 + wn * 64 + ni * 16 + cB];

    for (int it = 0; it < 8; ++it) {
        const int k0 = it * 32;
#pragma unroll
        for (int sw = 0; sw < 4; ++sw) {
            int e = sw * 256 + tid;
            int row = e >> 3, kq = e & 7;
            float4 v = *((const float4*)(x + (size_t)(m0 + row) * Ff + k0) + kq);
            unsigned short h0 = f2bf(v.x), h1 = f2bf(v.y), h2 = f2bf(v.z), h3 = f2bf(v.w);
            unsigned short l0 = f2bf(v.x - bf2f(h0)), l1 = f2bf(v.y - bf2f(h1));
            unsigned short l2 = f2bf(v.z - bf2f(h2)), l3 = f2bf(v.w - bf2f(h3));
            uint2 ph, pl;
            ph.x = (unsigned)h0 | ((unsigned)h1 << 16); ph.y = (unsigned)h2 | ((unsigned)h3 << 16);
            pl.x = (unsigned)l0 | ((unsigned)l1 << 16); pl.y = (unsigned)l2 | ((unsigned)l3 << 16);
            *(uint2*)(&Ahi[row * 40 + kq * 4]) = ph;
            *(uint2*)(&Alo[row * 40 + kq * 4]) = pl;
        }
#pragma unroll
        for (int sw = 0; sw < 4; ++sw) {
            int e = sw * 256 + tid;
            int kr = e >> 5, nq = e & 31;
            float4 v = *((const float4*)(w + (size_t)(k0 + kr) * G4 + n0) + nq);
            int nb = nq * 4;
            Wt[(nb + 0) * 40 + kr] = f2bf(v.x);
            Wt[(nb + 1) * 40 + kr] = f2bf(v.y);
            Wt[(nb + 2) * 40 + kr] = f2bf(v.z);
            Wt[(nb + 3) * 40 + kr] = f2bf(v.w);
        }
        __syncthreads();

        short8 bfr[4];
#pragma unroll
        for (int ni = 0; ni < 4; ++ni)
            bfr[ni] = *(const short8*)(&Wt[(wn * 64 + ni * 16 + cB) * 40 + kgrp * 8]);
#pragma unroll
        for (int mi = 0; mi < 4; ++mi) {
            short8 ah = *(const short8*)(&Ahi[(wm * 64 + mi * 16 + cB) * 40 + kgrp * 8]);
            short8 al = *(const short8*)(&Alo[(wm * 64 + mi * 16 + cB) * 40 + kgrp * 8]);
#pragma unroll
            for (int ni = 0; ni < 4; ++ni) {
                acc[mi][ni] = __builtin_amdgcn_mfma_f32_16x16x32_bf16(ah, bfr[ni], acc[mi][ni], 0, 0, 0);
                acc[mi][ni] = __builtin_amdgcn_mfma_f32_16x16x32_bf16(al, bfr[ni], acc[mi][ni], 0, 0, 0);
            }
        }
        __syncthreads();
    }
#pragma unroll
    for (int mi = 0; mi < 4; ++mi)
#pragma unroll
        for (int ni = 0; ni < 4; ++ni) {
            int rowb = m0 + wm * 64 + mi * 16 + kgrp * 4;
            int col = n0 + wn * 64 + ni * 16 + cB;
#pragma unroll
            for (int rr = 0; rr < 4; ++rr)
                xzh[(size_t)(rowb + rr) * G4 + col] = (_Float16)(acc[mi][ni][rr] + bv[ni]);
        }
}

// ---------------------------------------------------------------------------
// Kernel R: persistent scan, fence-free device-scope sync.
// Grid 512 = 8 row-groups x 64 col-blocks. 256 thr (4 waves: t2 x kh).
// Elementwise: wave 0 only, 64 threads x 2 cells (dword-granular h exchange).
// ---------------------------------------------------------------------------
__global__ __launch_bounds__(256, 2) void lstm_rec(
    const _Float16* __restrict__ xzh, const float* __restrict__ rk,
    unsigned* __restrict__ hbuf_u, unsigned* __restrict__ bar,
    float* __restrict__ out)
{
    __shared__ unsigned short Rlds[32 * 520];
    __shared__ unsigned short hlds[16 * 520];
    __shared__ float zbuf[4 * 256];

    const int tid = threadIdx.x;
    const int idx = blockIdx.x;
    const int rg = idx & 7;          // row group (likely same-XCD under round-robin; perf only)
    const int cb = idx >> 3;         // 0..63
    const int b0 = rg * 16;
    const int hc0 = cb * 8;

    const int lane = tid & 63;
    const int wv = tid >> 6;
    const int t2 = wv & 1;
    const int kh = wv >> 1;
    const int cB = lane & 15, kgrp = lane >> 4;

    // preload R slice: Rlds[n][k], n = t2*16+sub, gate = t2*2 + (sub>>3), hcol = sub&7
    for (int e = tid; e < 32 * 512; e += 256) {
        int k = e >> 5, n = e & 31;
        int gate = ((n >> 4) << 1) | ((n >> 3) & 1);
        int col = gate * 512 + hc0 + (n & 7);
        Rlds[n * 520 + k] = f2bf(rk[(size_t)k * G4 + col]);
    }

    unsigned* hb0 = hbuf_u;                       // 128*256 uints (2 bf16 each)
    unsigned* hb1 = hbuf_u + (size_t)Bb * Hh / 2;
    unsigned* cnt = bar + rg * 32;
    unsigned* gen = bar + 256 + rg * 32;
    unsigned local_gen = 0;

    // elementwise ownership: wave 0, 64 threads, 2 cells each
    const int r = tid >> 2;          // 0..15
    const int cp = tid & 3;          // col pair -> cols 2cp, 2cp+1
    const int b = b0 + r;
    const bool ew = (tid < 64);
    float creg0 = 0.f, creg1 = 0.f;
    float xzr[8];                    // [gate*2 + cell]
    const unsigned* xz_u = (const unsigned*)xzh;
    if (ew) {
#pragma unroll
        for (int g = 0; g < 4; ++g) {
            unsigned v = xz_u[(((size_t)b * Tt + 0) * G4 + g * 512 + hc0) / 2 + cp];
            xzr[2 * g]     = (float)__builtin_bit_cast(_Float16, (unsigned short)(v & 0xffffu));
            xzr[2 * g + 1] = (float)__builtin_bit_cast(_Float16, (unsigned short)(v >> 16));
        }
    }
    __syncthreads();

    unsigned* hlds_u = (unsigned*)hlds;

    for (int t = 0; t < Tt; ++t) {
        const unsigned* hrd = (t & 1) ? hb1 : hb0;
        unsigned* hwr = (t & 1) ? hb0 : hb1;

        // stage h tile (16 rows x 256 dwords) via device-relaxed loads (sc1)
        const unsigned* hbr = hrd + (size_t)b0 * 256;
#pragma unroll
        for (int i = 0; i < 16; ++i) {
            unsigned v = __hip_atomic_load(hbr + i * 256 + tid, __ATOMIC_RELAXED,
                                           __HIP_MEMORY_SCOPE_AGENT);
            hlds_u[i * 260 + tid] = v;   // pitch 520 shorts = 260 dwords
        }
        __syncthreads();

        // z-tile GEMM: 1 MFMA-tile per wave, K-half of 256
        floatx4 acc = (floatx4){0.f, 0.f, 0.f, 0.f};
        {
            const unsigned short* ap = &hlds[cB * 520 + kh * 256 + kgrp * 8];
            const unsigned short* bp = &Rlds[(t2 * 16 + cB) * 520 + kh * 256 + kgrp * 8];
#pragma unroll
            for (int kk = 0; kk < 8; ++kk) {
                short8 a = *(const short8*)(ap + kk * 32);
                short8 bb = *(const short8*)(bp + kk * 32);
                acc = __builtin_amdgcn_mfma_f32_16x16x32_bf16(a, bb, acc, 0, 0, 0);
            }
        }
        {
            float* zp = &zbuf[wv * 256 + kgrp * 64 + cB];  // row=kgrp*4+reg, col=cB
            zp[0]  = acc[0];
            zp[16] = acc[1];
            zp[32] = acc[2];
            zp[48] = acc[3];
        }
        __syncthreads();

        if (ew) {
            const int base = r * 16;
            const int c0 = 2 * cp, c1 = 2 * cp + 1;
            float zi0 = zbuf[base + c0]       + zbuf[512 + base + c0]       + xzr[0];
            float zi1 = zbuf[base + c1]       + zbuf[512 + base + c1]       + xzr[1];
            float zf0 = zbuf[base + 8 + c0]   + zbuf[512 + base + 8 + c0]   + xzr[2];
            float zf1 = zbuf[base + 8 + c1]   + zbuf[512 + base + 8 + c1]   + xzr[3];
            float zg0 = zbuf[256 + base + c0] + zbuf[768 + base + c0]       + xzr[4];
            float zg1 = zbuf[256 + base + c1] + zbuf[768 + base + c1]       + xzr[5];
            float zo0 = zbuf[256 + base + 8 + c0] + zbuf[768 + base + 8 + c0] + xzr[6];
            float zo1 = zbuf[256 + base + 8 + c1] + zbuf[768 + base + 8 + c1] + xzr[7];
            creg0 = sigm(zf0) * creg0 + sigm(zi0) * tanh_f(zg0);
            creg1 = sigm(zf1) * creg1 + sigm(zi1) * tanh_f(zg1);
            float hv0 = sigm(zo0) * tanh_f(creg0);
            float hv1 = sigm(zo1) * tanh_f(creg1);
            // output (cached store; visibility handled at kernel end)
            *(float2*)(out + ((size_t)b * Tt + t) * Hh + hc0 + c0) = make_float2(hv0, hv1);
            // h exchange: device-relaxed sc1 store (bypasses non-coherent L2)
            unsigned hp = (unsigned)f2bf(hv0) | ((unsigned)f2bf(hv1) << 16);
            __hip_atomic_store(hwr + (size_t)b * 256 + (hc0 >> 1) + cp, hp,
                               __ATOMIC_RELAXED, __HIP_MEMORY_SCOPE_AGENT);
            if (t < Tt - 1) {
                // prefetch next step's xz (normal cached loads; L2 never invalidated now)
#pragma unroll
                for (int g = 0; g < 4; ++g) {
                    unsigned v = xz_u[(((size_t)b * Tt + (t + 1)) * G4 + g * 512 + hc0) / 2 + cp];
                    xzr[2 * g]     = (float)__builtin_bit_cast(_Float16, (unsigned short)(v & 0xffffu));
                    xzr[2 * g + 1] = (float)__builtin_bit_cast(_Float16, (unsigned short)(v >> 16));
                }
            } else {
                float* hl = out + (size_t)Bb * Tt * Hh;
                float* cl = hl + (size_t)Bb * Hh;
                *(float2*)(hl + (size_t)b * Hh + hc0 + c0) = make_float2(hv0, hv1);
                *(float2*)(cl + (size_t)b * Hh + hc0 + c0) = make_float2(creg0, creg1);
            }
        }
        if (t == Tt - 1) break;

        // fence-free per-group barrier: monotonic counter + generation broadcast.
        // All ew work is in wave 0 (same wave as tid 0), so issue order is program
        // order; s_waitcnt vmcnt(0) makes the sc1 h-stores device-visible before
        // the counter bump. No acquire/release -> no L2 inv/wbl2.
        if (tid == 0) {
            asm volatile("s_waitcnt vmcnt(0)" ::: "memory");
            unsigned target = ++local_gen;
            unsigned old = __hip_atomic_fetch_add(cnt, 1u, __ATOMIC_RELAXED,
                                                  __HIP_MEMORY_SCOPE_AGENT);
            if (old == target * 64u - 1u) {
                __hip_atomic_store(gen, target, __ATOMIC_RELAXED, __HIP_MEMORY_SCOPE_AGENT);
            } else {
                while (__hip_atomic_load(gen, __ATOMIC_RELAXED, __HIP_MEMORY_SCOPE_AGENT) < target)
                    __builtin_amdgcn_s_sleep(1);
            }
        } else if (lane == 0) {
            // nothing: other waves just wait at the block barrier
        }
        __syncthreads();
    }
}

// ---------------------------------------------------------------------------
extern "C" void kernel_launch(void* const* d_in, const int* in_sizes, int n_in,
                              void* d_out, int out_size, void* d_ws, size_t ws_size,
                              hipStream_t stream) {
    (void)in_sizes; (void)n_in; (void)out_size; (void)ws_size;
    const float* x    = (const float*)d_in[0];
    const float* w    = (const float*)d_in[1];
    const float* rk   = (const float*)d_in[2];
    const float* bias = (const float*)d_in[3];
    float* out = (float*)d_out;

    char* ws = (char*)d_ws;
    const size_t XZ_BYTES   = (size_t)Bb * Tt * G4 * sizeof(_Float16);      // 268,435,456
    const size_t HBUF_BYTES = (size_t)2 * Bb * Hh * sizeof(unsigned short); // 262,144
    const size_t BAR_BYTES  = 2048;

    _Float16* xzh = (_Float16*)ws;
    unsigned* hbuf = (unsigned*)(ws + XZ_BYTES);
    unsigned* bar = (unsigned*)(ws + XZ_BYTES + HBUF_BYTES);

    hipMemsetAsync(ws + XZ_BYTES, 0, HBUF_BYTES + BAR_BYTES, stream);

    lstm_xz<<<dim3(8192), dim3(256), 0, stream>>>(x, w, bias, xzh);
    lstm_rec<<<dim3(512), dim3(256), 0, stream>>>(xzh, rk, hbuf, bar, out);
}